// Round 1
// baseline (1205.941 us; speedup 1.0000x reference)
//
#include <hip/hip_runtime.h>
#include <math.h>

#define M_TOT 8192   // B*S
#define DIM   512    // D
#define S_LEN 2048
#define NB    4
#define NH    8

// ---------------------------------------------------------------------------
// C[M_TOT, DIM] = A[M_TOT, DIM] @ Bw[DIM, DIM]   (fp32, 64x64 tile, BK=16)
// ---------------------------------------------------------------------------
__global__ __launch_bounds__(256) void gemm_f32(const float* __restrict__ A,
                                                const float* __restrict__ Bw,
                                                float* __restrict__ C) {
    __shared__ float As[16][64];   // k-major (transposed)
    __shared__ float Bs[16][64];   // k-major (natural)
    const int tid  = threadIdx.x;
    const int rg   = tid >> 4;     // 0..15 row group
    const int cg   = tid & 15;     // 0..15 col group
    const int row0 = blockIdx.x * 64;
    const int col0 = blockIdx.y * 64;
    // A load mapping: 64 rows x 4 float4 along k
    const int lr  = tid >> 2;      // 0..63 row
    const int lkq = tid & 3;       // 0..3  k-quad
    // B load mapping: 16 k-rows x 16 float4 along n
    const int lkr = tid >> 4;      // 0..15 k row
    const int lnv = tid & 15;      // 0..15 n-quad

    float acc[4][4] = {};

    float4 a4 = *(const float4*)&A[(size_t)(row0 + lr) * DIM + lkq * 4];
    float4 b4 = *(const float4*)&Bw[(size_t)lkr * DIM + col0 + lnv * 4];

    for (int kt = 0; kt < DIM; kt += 16) {
        __syncthreads();   // previous tile's compute done
        As[lkq * 4 + 0][lr] = a4.x;
        As[lkq * 4 + 1][lr] = a4.y;
        As[lkq * 4 + 2][lr] = a4.z;
        As[lkq * 4 + 3][lr] = a4.w;
        *(float4*)&Bs[lkr][lnv * 4] = b4;
        __syncthreads();
        // prefetch next tile (clamped reload on last iter; harmless)
        const int kn = (kt + 16 < DIM) ? kt + 16 : 0;
        a4 = *(const float4*)&A[(size_t)(row0 + lr) * DIM + kn + lkq * 4];
        b4 = *(const float4*)&Bw[(size_t)(kn + lkr) * DIM + col0 + lnv * 4];
        #pragma unroll
        for (int k = 0; k < 16; ++k) {
            float av[4], bv[4];
            *(float4*)av = *(const float4*)&As[k][rg * 4];
            *(float4*)bv = *(const float4*)&Bs[k][cg * 4];
            #pragma unroll
            for (int i = 0; i < 4; ++i)
                #pragma unroll
                for (int j = 0; j < 4; ++j)
                    acc[i][j] += av[i] * bv[j];
        }
    }
    #pragma unroll
    for (int i = 0; i < 4; ++i) {
        float4 o = make_float4(acc[i][0], acc[i][1], acc[i][2], acc[i][3]);
        *(float4*)&C[(size_t)(row0 + rg * 4 + i) * DIM + col0 + cg * 4] = o;
    }
}

// ---------------------------------------------------------------------------
// Attention: per (b, h, q-tile of 64). O = softmax(relu(QK^T/8)) V
// Softmax without max-subtraction (scores in [0, ~4] after ReLU -> safe).
// Qs/Ks XOR-swizzled (float4 granularity) to kill row-stride bank conflicts.
// O aliases Q in global ws (each block writes exactly the tile only it reads).
// ---------------------------------------------------------------------------
__global__ __launch_bounds__(256) void attn_f32(const float* Qg,
                                                const float* __restrict__ Kg,
                                                const float* __restrict__ Vg,
                                                float* Og) {
    __shared__ float Qs[64][64];     // swizzled [row][ (c4 ^ (row&15))*4 + k ]
    __shared__ float Ks[64][64];     // swizzled
    __shared__ float Vs[64][64];     // natural  [key][hd]
    __shared__ float Es[64][68];     // [key][q], stride 68 (16B aligned, conflict-free)
    __shared__ float dred[64][16];
    __shared__ float dinv[64];

    const int tid = threadIdx.x;
    const int rg  = tid >> 4;    // 0..15
    const int cg  = tid & 15;    // 0..15
    const int q0  = blockIdx.x * 64;
    const int bh  = blockIdx.y;
    const int b   = bh >> 3;
    const int h   = bh & 7;
    const size_t base = (size_t)(b * S_LEN) * DIM + h * 64;

    // ---- load Q tile (swizzled) ----
    #pragma unroll
    for (int it = 0; it < 4; ++it) {
        const int f = tid + it * 256;
        const int lrow = f >> 4, lc = f & 15;
        float4 v = *(const float4*)&Qg[base + (size_t)(q0 + lrow) * DIM + lc * 4];
        *(float4*)&Qs[lrow][(lc ^ (lrow & 15)) << 2] = v;
    }

    float acc[4][4]  = {};           // O numerator: rows rg*4+i, hd cols cg*4+j
    float dsum[4]    = {0.f, 0.f, 0.f, 0.f};  // denom partials: rows rg+16i

    // ---- prefetch K/V tile 0 ----
    float4 kreg[4], vreg[4];
    #pragma unroll
    for (int it = 0; it < 4; ++it) {
        const int f = tid + it * 256;
        const int lrow = f >> 4, lc = f & 15;
        kreg[it] = *(const float4*)&Kg[base + (size_t)lrow * DIM + lc * 4];
        vreg[it] = *(const float4*)&Vg[base + (size_t)lrow * DIM + lc * 4];
    }

    for (int kt = 0; kt < S_LEN; kt += 64) {
        __syncthreads();  // prev O-phase reads of Ks/Vs/Es complete
        #pragma unroll
        for (int it = 0; it < 4; ++it) {
            const int f = tid + it * 256;
            const int lrow = f >> 4, lc = f & 15;
            *(float4*)&Ks[lrow][(lc ^ (lrow & 15)) << 2] = kreg[it];
            *(float4*)&Vs[lrow][lc * 4] = vreg[it];
        }
        __syncthreads();
        // prefetch next K/V tile (overlaps S-compute)
        const int ktn = (kt + 64 < S_LEN) ? kt + 64 : 0;
        #pragma unroll
        for (int it = 0; it < 4; ++it) {
            const int f = tid + it * 256;
            const int lrow = f >> 4, lc = f & 15;
            kreg[it] = *(const float4*)&Kg[base + (size_t)(ktn + lrow) * DIM + lc * 4];
            vreg[it] = *(const float4*)&Vg[base + (size_t)(ktn + lrow) * DIM + lc * 4];
        }

        // ---- S = Q K^T : thread rows {rg+16i}, keys {cg+16j} ----
        float s[4][4] = {};
        #pragma unroll
        for (int dc = 0; dc < 16; ++dc) {
            float qv[4][4], kv[4][4];
            #pragma unroll
            for (int i = 0; i < 4; ++i)
                *(float4*)qv[i] = *(const float4*)&Qs[rg + 16 * i][(dc ^ rg) << 2];
            #pragma unroll
            for (int j = 0; j < 4; ++j)
                *(float4*)kv[j] = *(const float4*)&Ks[cg + 16 * j][(dc ^ cg) << 2];
            #pragma unroll
            for (int i = 0; i < 4; ++i)
                #pragma unroll
                for (int j = 0; j < 4; ++j)
                    s[i][j] += qv[i][0] * kv[j][0] + qv[i][1] * kv[j][1]
                             + qv[i][2] * kv[j][2] + qv[i][3] * kv[j][3];
        }

        // ---- e = exp(relu(s/8)); note relu'd-to-0 entries contribute exp(0)=1 ----
        #pragma unroll
        for (int i = 0; i < 4; ++i)
            #pragma unroll
            for (int j = 0; j < 4; ++j) {
                const float sc = s[i][j] * 0.125f;
                const float e  = sc > 0.0f ? __expf(sc) : 1.0f;
                dsum[i] += e;
                Es[cg + 16 * j][rg + 16 * i] = e;
            }
        __syncthreads();  // Es complete; Qs/Ks reads complete

        // ---- O += E @ V : thread rows rg*4+i, hd cols cg*4+j ----
        #pragma unroll 8
        for (int kc = 0; kc < 64; ++kc) {
            float ev[4], vv[4];
            *(float4*)ev = *(const float4*)&Es[kc][rg * 4];
            *(float4*)vv = *(const float4*)&Vs[kc][cg * 4];
            #pragma unroll
            for (int i = 0; i < 4; ++i)
                #pragma unroll
                for (int j = 0; j < 4; ++j)
                    acc[i][j] += ev[i] * vv[j];
        }
    }

    // ---- reduce denominators across the 16 cg groups ----
    __syncthreads();
    #pragma unroll
    for (int i = 0; i < 4; ++i) dred[rg + 16 * i][cg] = dsum[i];
    __syncthreads();
    if (tid < 64) {
        float t = 0.f;
        #pragma unroll
        for (int c = 0; c < 16; ++c) t += dred[tid][c];
        dinv[tid] = 1.0f / t;
    }
    __syncthreads();

    // ---- normalize + store (merged-head [B,S,D] layout) ----
    #pragma unroll
    for (int i = 0; i < 4; ++i) {
        const float r = dinv[rg * 4 + i];
        float4 o = make_float4(acc[i][0] * r, acc[i][1] * r, acc[i][2] * r, acc[i][3] * r);
        *(float4*)&Og[base + (size_t)(q0 + rg * 4 + i) * DIM + cg * 4] = o;
    }
}

// ---------------------------------------------------------------------------
extern "C" void kernel_launch(void* const* d_in, const int* in_sizes, int n_in,
                              void* d_out, int out_size, void* d_ws, size_t ws_size,
                              hipStream_t stream) {
    const float* X  = (const float*)d_in[0];
    const float* Y  = (const float*)d_in[1];
    const float* Z  = (const float*)d_in[2];
    const float* Wq = (const float*)d_in[3];
    const float* Wk = (const float*)d_in[4];
    // d_in[5] = Wv is dead in the reference forward
    const float* Wo = (const float*)d_in[6];

    float* ws = (float*)d_ws;
    float* Q  = ws;                              // 8192*512 fp32; reused as attn output O
    float* K  = ws + (size_t)M_TOT * DIM;
    float* V  = ws + 2 * (size_t)M_TOT * DIM;    // total ws use: 48 MB

    const dim3 gg(M_TOT / 64, DIM / 64);
    gemm_f32<<<gg, 256, 0, stream>>>(X, Wq, Q);
    gemm_f32<<<gg, 256, 0, stream>>>(Y, Wk, K);
    gemm_f32<<<gg, 256, 0, stream>>>(Z, Wo, V);  // reference quirk: V uses Wo
    attn_f32<<<dim3(S_LEN / 64, NB * NH), 256, 0, stream>>>(Q, K, V, Q);
    gemm_f32<<<gg, 256, 0, stream>>>(Q, Wo, (float*)d_out);
}

// Round 2
// 233.436 us; speedup vs baseline: 5.1661x; 5.1661x over previous
//
#include <hip/hip_runtime.h>
#include <math.h>

#define S_LEN 2048
#define DIM   512
#define NB    4
#define NH    8
#define M_TOT 8192

typedef __attribute__((ext_vector_type(8))) short bf16x8;
typedef __attribute__((ext_vector_type(4))) short bf16x4;
typedef __attribute__((ext_vector_type(4))) float f32x4;

#define MFMA(a, b, c) __builtin_amdgcn_mfma_f32_16x16x32_bf16((a), (b), (c), 0, 0, 0)

__device__ __forceinline__ short f2b(float x) {
    union { float f; unsigned u; } v; v.f = x;
    unsigned r = v.u + 0x7FFFu + ((v.u >> 16) & 1u);   // RNE
    return (short)(r >> 16);
}

// ---------------------------------------------------------------------------
// Wt[n][k] bf16 = transpose+convert of W[k][n] f32. 64x64 tiles. z = which W.
// ---------------------------------------------------------------------------
__global__ __launch_bounds__(256) void prep_wt(const float* Wq, const float* Wk, const float* Wo,
                                               short* Wtq, short* Wtk, short* Wto) {
    const int zi = blockIdx.z;
    const float* W = zi == 0 ? Wq : zi == 1 ? Wk : Wo;
    short*      Wt = zi == 0 ? Wtq : zi == 1 ? Wtk : Wto;
    __shared__ short Ts[64 * 72];
    const int t = threadIdx.x;
    const int k0 = blockIdx.x * 64, n0 = blockIdx.y * 64;
    #pragma unroll
    for (int it = 0; it < 4; ++it) {
        const int r = (t >> 4) + 16 * it;      // k row
        const int cq = t & 15;                 // n quad
        float4 v = *(const float4*)&W[(size_t)(k0 + r) * DIM + n0 + cq * 4];
        Ts[(4 * cq + 0) * 72 + r] = f2b(v.x);
        Ts[(4 * cq + 1) * 72 + r] = f2b(v.y);
        Ts[(4 * cq + 2) * 72 + r] = f2b(v.z);
        Ts[(4 * cq + 3) * 72 + r] = f2b(v.w);
    }
    __syncthreads();
    #pragma unroll
    for (int it = 0; it < 2; ++it) {
        const int n = (t >> 3) + 32 * it;
        const int sg = t & 7;
        *(bf16x8*)&Wt[(size_t)(n0 + n) * DIM + k0 + sg * 8] = *(const bf16x8*)&Ts[n * 72 + sg * 8];
    }
}

// ---------------------------------------------------------------------------
// Projection GEMMs (fused 3): C_bf16[M,512] = A_f32[M,512] @ Wt^T.
// Tile 128(m) x 64(n), BK=32, 4 waves each 64x32. m97 gemm_bt pattern.
// ---------------------------------------------------------------------------
__global__ __launch_bounds__(256) void proj_gemm(const float* X, const float* Y, const float* Z,
                                                 const short* Wtq, const short* Wtk, const short* Wto,
                                                 short* Qb, short* Kb, short* Vb) {
    const int zi = blockIdx.z;
    const float* A  = zi == 0 ? X : zi == 1 ? Y : Z;
    const short* Wt = zi == 0 ? Wtq : zi == 1 ? Wtk : Wto;
    short*       C  = zi == 0 ? Qb : zi == 1 ? Kb : Vb;

    __shared__ short As[128 * 40];
    __shared__ short Bs[64 * 40];
    const int tid = threadIdx.x;
    const int w = tid >> 6, ln = tid & 63, l15 = ln & 15, quad = ln >> 4;
    const int m0 = blockIdx.x * 128, n0 = blockIdx.y * 64;
    const int wm = (w & 1) * 64, wn = (w >> 1) * 32;

    const float* ap = A + (size_t)(m0 + (tid >> 3)) * DIM + (tid & 7) * 4;
    const short* bp = Wt + (size_t)(n0 + (tid >> 2)) * DIM + (tid & 3) * 8;

    float4 ar[4]; bf16x8 br;
    #pragma unroll
    for (int it = 0; it < 4; ++it) ar[it] = *(const float4*)(ap + (size_t)32 * it * DIM);
    br = *(const bf16x8*)bp;

    f32x4 acc[4][2] = {};

    for (int k0 = 0; k0 < DIM; k0 += 32) {
        __syncthreads();
        #pragma unroll
        for (int it = 0; it < 4; ++it) {
            const int m = (tid >> 3) + 32 * it, kq = tid & 7;
            bf16x4 h = { f2b(ar[it].x), f2b(ar[it].y), f2b(ar[it].z), f2b(ar[it].w) };
            *(bf16x4*)&As[m * 40 + kq * 4] = h;
        }
        *(bf16x8*)&Bs[(tid >> 2) * 40 + (tid & 3) * 8] = br;
        __syncthreads();
        const int kn = (k0 + 32 < DIM) ? k0 + 32 : 0;
        #pragma unroll
        for (int it = 0; it < 4; ++it) ar[it] = *(const float4*)(ap + (size_t)32 * it * DIM + kn);
        br = *(const bf16x8*)(bp + kn);

        bf16x8 af[4], bf[2];
        #pragma unroll
        for (int mf = 0; mf < 4; ++mf) af[mf] = *(const bf16x8*)&As[(wm + 16 * mf + l15) * 40 + quad * 8];
        #pragma unroll
        for (int nf = 0; nf < 2; ++nf) bf[nf] = *(const bf16x8*)&Bs[(wn + 16 * nf + l15) * 40 + quad * 8];
        #pragma unroll
        for (int mf = 0; mf < 4; ++mf)
            #pragma unroll
            for (int nf = 0; nf < 2; ++nf)
                acc[mf][nf] = MFMA(af[mf], bf[nf], acc[mf][nf]);
    }
    #pragma unroll
    for (int mf = 0; mf < 4; ++mf)
        #pragma unroll
        for (int nf = 0; nf < 2; ++nf)
            #pragma unroll
            for (int r = 0; r < 4; ++r)
                C[(size_t)(m0 + wm + 16 * mf + 4 * quad + r) * DIM + n0 + wn + 16 * nf + l15] =
                    f2b(acc[mf][nf][r]);
}

// ---------------------------------------------------------------------------
// Final GEMM: Cout_f32 = Ob_bf16 @ Wto^T. Same structure, bf16 A staging.
// ---------------------------------------------------------------------------
__global__ __launch_bounds__(256) void out_gemm(const short* Ob, const short* Wto, float* Cout) {
    __shared__ short As[128 * 40];
    __shared__ short Bs[64 * 40];
    const int tid = threadIdx.x;
    const int w = tid >> 6, ln = tid & 63, l15 = ln & 15, quad = ln >> 4;
    const int m0 = blockIdx.x * 128, n0 = blockIdx.y * 64;
    const int wm = (w & 1) * 64, wn = (w >> 1) * 32;

    const short* ap = Ob + (size_t)(m0 + (tid >> 2)) * DIM + (tid & 3) * 8;
    const short* bp = Wto + (size_t)(n0 + (tid >> 2)) * DIM + (tid & 3) * 8;

    bf16x8 ar[2], br;
    ar[0] = *(const bf16x8*)ap;
    ar[1] = *(const bf16x8*)(ap + (size_t)64 * DIM);
    br = *(const bf16x8*)bp;

    f32x4 acc[4][2] = {};

    for (int k0 = 0; k0 < DIM; k0 += 32) {
        __syncthreads();
        *(bf16x8*)&As[(tid >> 2) * 40 + (tid & 3) * 8] = ar[0];
        *(bf16x8*)&As[((tid >> 2) + 64) * 40 + (tid & 3) * 8] = ar[1];
        *(bf16x8*)&Bs[(tid >> 2) * 40 + (tid & 3) * 8] = br;
        __syncthreads();
        const int kn = (k0 + 32 < DIM) ? k0 + 32 : 0;
        ar[0] = *(const bf16x8*)(ap + kn);
        ar[1] = *(const bf16x8*)(ap + (size_t)64 * DIM + kn);
        br = *(const bf16x8*)(bp + kn);

        bf16x8 af[4], bf[2];
        #pragma unroll
        for (int mf = 0; mf < 4; ++mf) af[mf] = *(const bf16x8*)&As[(wm + 16 * mf + l15) * 40 + quad * 8];
        #pragma unroll
        for (int nf = 0; nf < 2; ++nf) bf[nf] = *(const bf16x8*)&Bs[(wn + 16 * nf + l15) * 40 + quad * 8];
        #pragma unroll
        for (int mf = 0; mf < 4; ++mf)
            #pragma unroll
            for (int nf = 0; nf < 2; ++nf)
                acc[mf][nf] = MFMA(af[mf], bf[nf], acc[mf][nf]);
    }
    #pragma unroll
    for (int mf = 0; mf < 4; ++mf)
        #pragma unroll
        for (int nf = 0; nf < 2; ++nf)
            #pragma unroll
            for (int r = 0; r < 4; ++r)
                Cout[(size_t)(m0 + wm + 16 * mf + 4 * quad + r) * DIM + n0 + wn + 16 * nf + l15] =
                    acc[mf][nf][r];
}

// ---------------------------------------------------------------------------
// Attention: block = (128 q) x (b,h). Phase1 S^T = K*Q^T (MFMA), exp (no max
// subtraction: post-ReLU scores in [0,~4], denom >= 2048), E via per-wave LDS
// roundtrip, Phase2 O = E*V via V transposed during LDS staging.
// ---------------------------------------------------------------------------
__global__ __launch_bounds__(256) void attn_mfma(const short* __restrict__ Qb,
                                                 const short* __restrict__ Kb,
                                                 const short* __restrict__ Vb,
                                                 short* __restrict__ Ob) {
    __shared__ short Ks[64 * 72];        // [key][hd], stride 72
    __shared__ short Vs[64 * 72];        // [hd][key] (transposed), stride 72
    __shared__ short Es[4][32 * 72];     // per-wave [q_local][key], stride 72
    __shared__ float Dinv[128];

    const int tid = threadIdx.x;
    const int w = tid >> 6, ln = tid & 63, l15 = ln & 15, quad = ln >> 4;
    const int qt0 = blockIdx.x * 128;
    const int bh = blockIdx.y;
    const int b = bh >> 3, h = bh & 7;
    const size_t tokbase = (size_t)b * S_LEN;

    // Q fragments (B-operand of phase 1), resident all kernel:
    // qf[nf][ks]: lane holds Q[q = qt0+32w+16nf+l15][hd = 32ks+8quad+j]
    bf16x8 qf[2][2];
    #pragma unroll
    for (int nf = 0; nf < 2; ++nf)
        #pragma unroll
        for (int ks = 0; ks < 2; ++ks)
            qf[nf][ks] = *(const bf16x8*)&Qb[(tokbase + qt0 + 32 * w + 16 * nf + l15) * DIM +
                                             h * 64 + 32 * ks + 8 * quad];

    // staging pointers: thread stages rows r=tid>>3 and r+32, seg sg=tid&7
    const short* kbase = Kb + (tokbase + (tid >> 3)) * DIM + h * 64 + (tid & 7) * 8;
    const short* vbase = Vb + (tokbase + (tid >> 3)) * DIM + h * 64 + (tid & 7) * 8;

    bf16x8 kreg0 = *(const bf16x8*)kbase;
    bf16x8 kreg1 = *(const bf16x8*)(kbase + (size_t)32 * DIM);
    bf16x8 vreg0 = *(const bf16x8*)vbase;
    bf16x8 vreg1 = *(const bf16x8*)(vbase + (size_t)32 * DIM);

    f32x4 oacc[2][4] = {};
    float dsum[2] = {0.f, 0.f};

    for (int kc = 0; kc < S_LEN / 64; ++kc) {
        __syncthreads();
        {
            const int r = tid >> 3, sg = tid & 7;
            *(bf16x8*)&Ks[r * 72 + sg * 8] = kreg0;
            *(bf16x8*)&Ks[(r + 32) * 72 + sg * 8] = kreg1;
            #pragma unroll
            for (int j = 0; j < 8; ++j) Vs[(sg * 8 + j) * 72 + r] = vreg0[j];
            #pragma unroll
            for (int j = 0; j < 8; ++j) Vs[(sg * 8 + j) * 72 + r + 32] = vreg1[j];
        }
        __syncthreads();
        {   // prefetch next chunk (clamped reload on last iter)
            const size_t off = (size_t)((kc + 1 < S_LEN / 64) ? kc + 1 : kc) * 64 * DIM;
            kreg0 = *(const bf16x8*)(kbase + off);
            kreg1 = *(const bf16x8*)(kbase + off + (size_t)32 * DIM);
            vreg0 = *(const bf16x8*)(vbase + off);
            vreg1 = *(const bf16x8*)(vbase + off + (size_t)32 * DIM);
        }

        // ---- phase 1: S^T[key][q] = K * Q^T ----
        f32x4 sacc[4][2];
        #pragma unroll
        for (int mf = 0; mf < 4; ++mf) {
            bf16x8 a0 = *(const bf16x8*)&Ks[(16 * mf + l15) * 72 + 8 * quad];
            bf16x8 a1 = *(const bf16x8*)&Ks[(16 * mf + l15) * 72 + 32 + 8 * quad];
            #pragma unroll
            for (int nf = 0; nf < 2; ++nf) {
                f32x4 s = {0.f, 0.f, 0.f, 0.f};
                s = MFMA(a0, qf[nf][0], s);
                s = MFMA(a1, qf[nf][1], s);
                sacc[mf][nf] = s;
            }
        }

        // ---- exp(relu(s/8)) -> E (bf16, per-wave LDS), denom partials ----
        #pragma unroll
        for (int mf = 0; mf < 4; ++mf)
            #pragma unroll
            for (int nf = 0; nf < 2; ++nf) {
                bf16x4 e4;
                #pragma unroll
                for (int r = 0; r < 4; ++r) {
                    const float sc = sacc[mf][nf][r] * 0.125f;
                    const float e = sc > 0.f ? __expf(sc) : 1.0f;
                    dsum[nf] += e;
                    e4[r] = f2b(e);
                }
                // keys 16mf+4quad..+3 contiguous in row q_local = 16nf+l15
                *(bf16x4*)&Es[w][(16 * nf + l15) * 72 + 16 * mf + 4 * quad] = e4;
            }

        // ---- phase 2: O[q][hd] += E * V ----
        #pragma unroll
        for (int ks2 = 0; ks2 < 2; ++ks2) {
            bf16x8 e0 = *(const bf16x8*)&Es[w][l15 * 72 + 32 * ks2 + 8 * quad];
            bf16x8 e1 = *(const bf16x8*)&Es[w][(16 + l15) * 72 + 32 * ks2 + 8 * quad];
            #pragma unroll
            for (int nf2 = 0; nf2 < 4; ++nf2) {
                bf16x8 vf = *(const bf16x8*)&Vs[(l15 + 16 * nf2) * 72 + 32 * ks2 + 8 * quad];
                oacc[0][nf2] = MFMA(e0, vf, oacc[0][nf2]);
                oacc[1][nf2] = MFMA(e1, vf, oacc[1][nf2]);
            }
        }
    }

    // ---- denominators: butterfly over quads, then per-row inverse ----
    #pragma unroll
    for (int nf = 0; nf < 2; ++nf) {
        dsum[nf] += __shfl_xor(dsum[nf], 16);
        dsum[nf] += __shfl_xor(dsum[nf], 32);
    }
    if (quad == 0) {
        Dinv[32 * w + l15] = 1.0f / dsum[0];
        Dinv[32 * w + 16 + l15] = 1.0f / dsum[1];
    }
    __syncthreads();

    // ---- normalize + store bf16 ----
    #pragma unroll
    for (int mf2 = 0; mf2 < 2; ++mf2)
        #pragma unroll
        for (int r = 0; r < 4; ++r) {
            const int ql = 16 * mf2 + 4 * quad + r;             // 0..31 within wave
            const float di = Dinv[32 * w + ql];
            const size_t row = (tokbase + qt0 + 32 * w + ql) * DIM + h * 64;
            #pragma unroll
            for (int nf2 = 0; nf2 < 4; ++nf2)
                Ob[row + 16 * nf2 + l15] = f2b(oacc[mf2][nf2][r] * di);
        }
}

// ---------------------------------------------------------------------------
extern "C" void kernel_launch(void* const* d_in, const int* in_sizes, int n_in,
                              void* d_out, int out_size, void* d_ws, size_t ws_size,
                              hipStream_t stream) {
    const float* X  = (const float*)d_in[0];
    const float* Y  = (const float*)d_in[1];
    const float* Z  = (const float*)d_in[2];
    const float* Wq = (const float*)d_in[3];
    const float* Wk = (const float*)d_in[4];
    // d_in[5] = Wv dead in reference forward
    const float* Wo = (const float*)d_in[6];

    char* p = (char*)d_ws;
    const size_t MD = (size_t)M_TOT * DIM;           // 4.19M elems
    short* Qb  = (short*)p;            p += MD * 2;  // 8 MB each
    short* Kb  = (short*)p;            p += MD * 2;
    short* Vb  = (short*)p;            p += MD * 2;
    short* Ob  = (short*)p;            p += MD * 2;
    short* Wtq = (short*)p;            p += (size_t)DIM * DIM * 2;
    short* Wtk = (short*)p;            p += (size_t)DIM * DIM * 2;
    short* Wto = (short*)p;            p += (size_t)DIM * DIM * 2;

    prep_wt<<<dim3(8, 8, 3), 256, 0, stream>>>(Wq, Wk, Wo, Wtq, Wtk, Wto);
    proj_gemm<<<dim3(64, 8, 3), 256, 0, stream>>>(X, Y, Z, Wtq, Wtk, Wto, Qb, Kb, Vb);
    attn_mfma<<<dim3(16, 32), 256, 0, stream>>>(Qb, Kb, Vb, Ob);
    out_gemm<<<dim3(64, 8), 256, 0, stream>>>(Ob, Wto, (float*)d_out);
}

// Round 3
// 215.819 us; speedup vs baseline: 5.5877x; 1.0816x over previous
//
#include <hip/hip_runtime.h>
#include <math.h>

#define S_LEN 2048
#define DIM   512
#define M_TOT 8192
#define NCH   (S_LEN / 64)

typedef __attribute__((ext_vector_type(8))) short bf16x8;
typedef __attribute__((ext_vector_type(4))) short bf16x4;
typedef __attribute__((ext_vector_type(4))) float f32x4;

#define MFMA(a, b, c) __builtin_amdgcn_mfma_f32_16x16x32_bf16((a), (b), (c), 0, 0, 0)

__device__ __forceinline__ short f2b(float x) {
    union { float f; unsigned u; } v; v.f = x;
    unsigned r = v.u + 0x7FFFu + ((v.u >> 16) & 1u);   // RNE
    return (short)(r >> 16);
}

// ---------------------------------------------------------------------------
// fp32 -> bf16 bulk convert (X,Y,Z). One thread per 8 floats.
// ---------------------------------------------------------------------------
__global__ __launch_bounds__(256) void cvt_bf16(const float* __restrict__ X,
                                                const float* __restrict__ Y,
                                                const float* __restrict__ Z,
                                                short* __restrict__ Xb,
                                                short* __restrict__ Yb,
                                                short* __restrict__ Zb) {
    const int zi = blockIdx.y;
    const float* A = zi == 0 ? X : zi == 1 ? Y : Z;
    short* O = zi == 0 ? Xb : zi == 1 ? Yb : Zb;
    const size_t i = (size_t)blockIdx.x * 256 + threadIdx.x;
    float4 a = ((const float4*)A)[2 * i];
    float4 b = ((const float4*)A)[2 * i + 1];
    bf16x8 o = { f2b(a.x), f2b(a.y), f2b(a.z), f2b(a.w),
                 f2b(b.x), f2b(b.y), f2b(b.z), f2b(b.w) };
    *(bf16x8*)&O[i * 8] = o;
}

// ---------------------------------------------------------------------------
// Wt[n][k] bf16 = transpose+convert of W[k][n] f32. 64x64 tiles.
// ---------------------------------------------------------------------------
__global__ __launch_bounds__(256) void prep_wt(const float* Wq, const float* Wk, const float* Wo,
                                               short* Wtq, short* Wtk, short* Wto) {
    const int zi = blockIdx.z;
    const float* W = zi == 0 ? Wq : zi == 1 ? Wk : Wo;
    short*      Wt = zi == 0 ? Wtq : zi == 1 ? Wtk : Wto;
    __shared__ short Ts[64 * 72];
    const int t = threadIdx.x;
    const int k0 = blockIdx.x * 64, n0 = blockIdx.y * 64;
    #pragma unroll
    for (int it = 0; it < 4; ++it) {
        const int r = (t >> 4) + 16 * it;
        const int cq = t & 15;
        float4 v = *(const float4*)&W[(size_t)(k0 + r) * DIM + n0 + cq * 4];
        Ts[(4 * cq + 0) * 72 + r] = f2b(v.x);
        Ts[(4 * cq + 1) * 72 + r] = f2b(v.y);
        Ts[(4 * cq + 2) * 72 + r] = f2b(v.z);
        Ts[(4 * cq + 3) * 72 + r] = f2b(v.w);
    }
    __syncthreads();
    #pragma unroll
    for (int it = 0; it < 2; ++it) {
        const int n = (t >> 3) + 32 * it;
        const int sg = t & 7;
        *(bf16x8*)&Wt[(size_t)(n0 + n) * DIM + k0 + sg * 8] = *(const bf16x8*)&Ts[n * 72 + sg * 8];
    }
}

// ---------------------------------------------------------------------------
// Projection GEMMs (fused 3): 128x128 tile, BK=32, 4 waves (2x2, each 64x64).
// All-bf16 staging (b128 LDS writes, stride 40 = conflict-spread).
// zi==2 (V) is stored TRANSPOSED per (b,h): Vt[((b*8+h)*64+hd)*2048 + s].
// ---------------------------------------------------------------------------
__global__ __launch_bounds__(256) void proj_gemm(const short* __restrict__ Xb,
                                                 const short* __restrict__ Yb,
                                                 const short* __restrict__ Zb,
                                                 const short* __restrict__ Wtq,
                                                 const short* __restrict__ Wtk,
                                                 const short* __restrict__ Wto,
                                                 short* __restrict__ Qb,
                                                 short* __restrict__ Kb,
                                                 short* __restrict__ Vt) {
    const int zi = blockIdx.z;
    const short* A  = zi == 0 ? Xb : zi == 1 ? Yb : Zb;
    const short* Bw = zi == 0 ? Wtq : zi == 1 ? Wtk : Wto;

    __shared__ short As[128 * 40];
    __shared__ short Bs[128 * 40];
    const int tid = threadIdx.x;
    const int w = tid >> 6, ln = tid & 63, l15 = ln & 15, quad = ln >> 4;
    const int m0 = blockIdx.x * 128, n0 = blockIdx.y * 128;
    const int wm = (w & 1) * 64, wn = (w >> 1) * 64;

    const int r0 = tid >> 2, r1 = r0 + 64;
    const int sg = tid & 3;
    const short* ap0 = A  + (size_t)(m0 + r0) * DIM + sg * 8;
    const short* ap1 = A  + (size_t)(m0 + r1) * DIM + sg * 8;
    const short* bp0 = Bw + (size_t)(n0 + r0) * DIM + sg * 8;
    const short* bp1 = Bw + (size_t)(n0 + r1) * DIM + sg * 8;

    bf16x8 a0 = *(const bf16x8*)ap0, a1 = *(const bf16x8*)ap1;
    bf16x8 b0 = *(const bf16x8*)bp0, b1 = *(const bf16x8*)bp1;

    f32x4 acc[4][4] = {};

    for (int k0 = 0; k0 < DIM; k0 += 32) {
        __syncthreads();
        *(bf16x8*)&As[r0 * 40 + sg * 8] = a0;
        *(bf16x8*)&As[r1 * 40 + sg * 8] = a1;
        *(bf16x8*)&Bs[r0 * 40 + sg * 8] = b0;
        *(bf16x8*)&Bs[r1 * 40 + sg * 8] = b1;
        __syncthreads();
        const int kn = (k0 + 32 < DIM) ? k0 + 32 : 0;
        a0 = *(const bf16x8*)(ap0 + kn); a1 = *(const bf16x8*)(ap1 + kn);
        b0 = *(const bf16x8*)(bp0 + kn); b1 = *(const bf16x8*)(bp1 + kn);

        bf16x8 af[4], bf[4];
        #pragma unroll
        for (int mf = 0; mf < 4; ++mf) af[mf] = *(const bf16x8*)&As[(wm + 16 * mf + l15) * 40 + quad * 8];
        #pragma unroll
        for (int nf = 0; nf < 4; ++nf) bf[nf] = *(const bf16x8*)&Bs[(wn + 16 * nf + l15) * 40 + quad * 8];
        #pragma unroll
        for (int mf = 0; mf < 4; ++mf)
            #pragma unroll
            for (int nf = 0; nf < 4; ++nf)
                acc[mf][nf] = MFMA(af[mf], bf[nf], acc[mf][nf]);
    }

    if (zi < 2) {
        short* C = zi == 0 ? Qb : Kb;
        #pragma unroll
        for (int mf = 0; mf < 4; ++mf)
            #pragma unroll
            for (int nf = 0; nf < 4; ++nf)
                #pragma unroll
                for (int r = 0; r < 4; ++r)
                    C[(size_t)(m0 + wm + 16 * mf + 4 * quad + r) * DIM + n0 + wn + 16 * nf + l15] =
                        f2b(acc[mf][nf][r]);
    } else {
        #pragma unroll
        for (int mf = 0; mf < 4; ++mf)
            #pragma unroll
            for (int nf = 0; nf < 4; ++nf) {
                const int col = n0 + wn + 16 * nf + l15;
                const int h = col >> 6, hd = col & 63;
                const int row0_ = m0 + wm + 16 * mf + 4 * quad;
                const int bb = row0_ >> 11, s0 = row0_ & 2047;
                bf16x4 o = { f2b(acc[mf][nf][0]), f2b(acc[mf][nf][1]),
                             f2b(acc[mf][nf][2]), f2b(acc[mf][nf][3]) };
                *(bf16x4*)&Vt[((size_t)((bb * 8 + h) * 64 + hd)) * S_LEN + s0] = o;
            }
    }
}

// ---------------------------------------------------------------------------
// Final GEMM: fp32 out = Ob_bf16 @ Wto^T. Same 128x128 structure.
// ---------------------------------------------------------------------------
__global__ __launch_bounds__(256) void out_gemm(const short* __restrict__ Ob,
                                                const short* __restrict__ Wto,
                                                float* __restrict__ Cout) {
    __shared__ short As[128 * 40];
    __shared__ short Bs[128 * 40];
    const int tid = threadIdx.x;
    const int w = tid >> 6, ln = tid & 63, l15 = ln & 15, quad = ln >> 4;
    const int m0 = blockIdx.x * 128, n0 = blockIdx.y * 128;
    const int wm = (w & 1) * 64, wn = (w >> 1) * 64;

    const int r0 = tid >> 2, r1 = r0 + 64;
    const int sg = tid & 3;
    const short* ap0 = Ob  + (size_t)(m0 + r0) * DIM + sg * 8;
    const short* ap1 = Ob  + (size_t)(m0 + r1) * DIM + sg * 8;
    const short* bp0 = Wto + (size_t)(n0 + r0) * DIM + sg * 8;
    const short* bp1 = Wto + (size_t)(n0 + r1) * DIM + sg * 8;

    bf16x8 a0 = *(const bf16x8*)ap0, a1 = *(const bf16x8*)ap1;
    bf16x8 b0 = *(const bf16x8*)bp0, b1 = *(const bf16x8*)bp1;

    f32x4 acc[4][4] = {};

    for (int k0 = 0; k0 < DIM; k0 += 32) {
        __syncthreads();
        *(bf16x8*)&As[r0 * 40 + sg * 8] = a0;
        *(bf16x8*)&As[r1 * 40 + sg * 8] = a1;
        *(bf16x8*)&Bs[r0 * 40 + sg * 8] = b0;
        *(bf16x8*)&Bs[r1 * 40 + sg * 8] = b1;
        __syncthreads();
        const int kn = (k0 + 32 < DIM) ? k0 + 32 : 0;
        a0 = *(const bf16x8*)(ap0 + kn); a1 = *(const bf16x8*)(ap1 + kn);
        b0 = *(const bf16x8*)(bp0 + kn); b1 = *(const bf16x8*)(bp1 + kn);

        bf16x8 af[4], bf[4];
        #pragma unroll
        for (int mf = 0; mf < 4; ++mf) af[mf] = *(const bf16x8*)&As[(wm + 16 * mf + l15) * 40 + quad * 8];
        #pragma unroll
        for (int nf = 0; nf < 4; ++nf) bf[nf] = *(const bf16x8*)&Bs[(wn + 16 * nf + l15) * 40 + quad * 8];
        #pragma unroll
        for (int mf = 0; mf < 4; ++mf)
            #pragma unroll
            for (int nf = 0; nf < 4; ++nf)
                acc[mf][nf] = MFMA(af[mf], bf[nf], acc[mf][nf]);
    }
    #pragma unroll
    for (int mf = 0; mf < 4; ++mf)
        #pragma unroll
        for (int nf = 0; nf < 4; ++nf)
            #pragma unroll
            for (int r = 0; r < 4; ++r)
                Cout[(size_t)(m0 + wm + 16 * mf + 4 * quad + r) * DIM + n0 + wn + 16 * nf + l15] =
                    acc[mf][nf][r];
}

// ---------------------------------------------------------------------------
// Attention: 4 waves x 32q = 128q per block, per (b,h). Double-buffered K/V
// LDS (1 barrier/chunk). V arrives pre-transposed (Vt) -> natural b128
// staging, no scatter. exp(relu(s)/8) = exp(max(s,0)*0.125), no max-sub
// softmax (denom >= 2048). Denominator reduced via shfl only.
// ---------------------------------------------------------------------------
__global__ __launch_bounds__(256) void attn_mfma(const short* __restrict__ Qb,
                                                 const short* __restrict__ Kb,
                                                 const short* __restrict__ Vtg,
                                                 short* __restrict__ Ob) {
    __shared__ short Ks[2][64 * 72];
    __shared__ short Vs[2][64 * 72];
    __shared__ short Es[4][32 * 72];

    const int tid = threadIdx.x;
    const int w = tid >> 6, ln = tid & 63, l15 = ln & 15, quad = ln >> 4;
    const int qt0 = blockIdx.x * 128;
    const int bh = blockIdx.y, b = bh >> 3, h = bh & 7;
    const size_t tokbase = (size_t)b * S_LEN;

    // resident Q fragments: wave w covers q rows [qt0+32w, qt0+32w+32)
    bf16x8 qf[2][2];
    #pragma unroll
    for (int nf = 0; nf < 2; ++nf)
        #pragma unroll
        for (int ks = 0; ks < 2; ++ks)
            qf[nf][ks] = *(const bf16x8*)&Qb[(tokbase + qt0 + 32 * w + 16 * nf + l15) * DIM +
                                             h * 64 + 32 * ks + 8 * quad];

    const int srow = tid >> 3, ssg = tid & 7;    // srow 0..31
    const short* kbase = Kb  + (tokbase + srow) * DIM + h * 64 + ssg * 8;
    const short* vbase = Vtg + ((size_t)bh * 64 + srow) * S_LEN + ssg * 8;

    bf16x8 k0r, k1r, v0r, v1r;

    f32x4 oacc[2][4] = {};
    float dsum[2] = {0.f, 0.f};

    // prologue: chunk0 -> buf0; prefetch chunk1 regs
    {
        k0r = *(const bf16x8*)kbase;
        k1r = *(const bf16x8*)(kbase + (size_t)32 * DIM);
        v0r = *(const bf16x8*)vbase;
        v1r = *(const bf16x8*)(vbase + (size_t)32 * S_LEN);
        *(bf16x8*)&Ks[0][srow * 72 + ssg * 8] = k0r;
        *(bf16x8*)&Ks[0][(srow + 32) * 72 + ssg * 8] = k1r;
        *(bf16x8*)&Vs[0][srow * 72 + ssg * 8] = v0r;
        *(bf16x8*)&Vs[0][(srow + 32) * 72 + ssg * 8] = v1r;
        k0r = *(const bf16x8*)(kbase + (size_t)64 * DIM);
        k1r = *(const bf16x8*)(kbase + (size_t)96 * DIM);
        v0r = *(const bf16x8*)(vbase + 64);
        v1r = *(const bf16x8*)(vbase + (size_t)32 * S_LEN + 64);
    }
    __syncthreads();

    for (int kc = 0; kc < NCH; ++kc) {
        const int cur = kc & 1;
        if (kc + 1 < NCH) {     // stage chunk kc+1 (regs) into other buffer
            *(bf16x8*)&Ks[cur ^ 1][srow * 72 + ssg * 8] = k0r;
            *(bf16x8*)&Ks[cur ^ 1][(srow + 32) * 72 + ssg * 8] = k1r;
            *(bf16x8*)&Vs[cur ^ 1][srow * 72 + ssg * 8] = v0r;
            *(bf16x8*)&Vs[cur ^ 1][(srow + 32) * 72 + ssg * 8] = v1r;
        }
        if (kc + 2 < NCH) {     // prefetch chunk kc+2 into regs
            const size_t ko = (size_t)(kc + 2) * 64 * DIM;
            const size_t vo = (size_t)(kc + 2) * 64;
            k0r = *(const bf16x8*)(kbase + ko);
            k1r = *(const bf16x8*)(kbase + ko + (size_t)32 * DIM);
            v0r = *(const bf16x8*)(vbase + vo);
            v1r = *(const bf16x8*)(vbase + vo + (size_t)32 * S_LEN);
        }

        // ---- phase 1: S^T[key][q] = K * Q^T ----
        f32x4 sacc[4][2];
        #pragma unroll
        for (int mf = 0; mf < 4; ++mf) {
            bf16x8 ka = *(const bf16x8*)&Ks[cur][(16 * mf + l15) * 72 + 8 * quad];
            bf16x8 kb = *(const bf16x8*)&Ks[cur][(16 * mf + l15) * 72 + 32 + 8 * quad];
            #pragma unroll
            for (int nf = 0; nf < 2; ++nf) {
                f32x4 s = {0.f, 0.f, 0.f, 0.f};
                s = MFMA(ka, qf[nf][0], s);
                s = MFMA(kb, qf[nf][1], s);
                sacc[mf][nf] = s;
            }
        }

        // ---- e = exp(max(s,0)/8) -> Es (per-wave, no barrier) ----
        short* Esw = &Es[w][0];
        #pragma unroll
        for (int mf = 0; mf < 4; ++mf)
            #pragma unroll
            for (int nf = 0; nf < 2; ++nf) {
                bf16x4 e4;
                #pragma unroll
                for (int r = 0; r < 4; ++r) {
                    const float e = __expf(fmaxf(sacc[mf][nf][r], 0.f) * 0.125f);
                    dsum[nf] += e;
                    e4[r] = f2b(e);
                }
                *(bf16x4*)&Esw[(16 * nf + l15) * 72 + 16 * mf + 4 * quad] = e4;
            }

        // ---- phase 2: O[q][hd] += E * V ----
        bf16x8 e00 = *(const bf16x8*)&Esw[l15 * 72 + 8 * quad];
        bf16x8 e01 = *(const bf16x8*)&Esw[l15 * 72 + 32 + 8 * quad];
        bf16x8 e10 = *(const bf16x8*)&Esw[(16 + l15) * 72 + 8 * quad];
        bf16x8 e11 = *(const bf16x8*)&Esw[(16 + l15) * 72 + 32 + 8 * quad];
        #pragma unroll
        for (int nf2 = 0; nf2 < 4; ++nf2) {
            bf16x8 vf0 = *(const bf16x8*)&Vs[cur][(16 * nf2 + l15) * 72 + 8 * quad];
            bf16x8 vf1 = *(const bf16x8*)&Vs[cur][(16 * nf2 + l15) * 72 + 32 + 8 * quad];
            oacc[0][nf2] = MFMA(e00, vf0, oacc[0][nf2]);
            oacc[0][nf2] = MFMA(e01, vf1, oacc[0][nf2]);
            oacc[1][nf2] = MFMA(e10, vf0, oacc[1][nf2]);
            oacc[1][nf2] = MFMA(e11, vf1, oacc[1][nf2]);
        }
        __syncthreads();
    }

    // ---- denominators: all-quad shfl reduction; all lanes get their l15's sum
    #pragma unroll
    for (int nf = 0; nf < 2; ++nf) {
        dsum[nf] += __shfl_xor(dsum[nf], 16);
        dsum[nf] += __shfl_xor(dsum[nf], 32);
    }
    const float dinv0 = 1.0f / dsum[0];
    const float dinv1 = 1.0f / dsum[1];

    // ---- normalize + store bf16 ----
    #pragma unroll
    for (int mf2 = 0; mf2 < 2; ++mf2) {
        const float dv = mf2 ? dinv1 : dinv0;
        #pragma unroll
        for (int r = 0; r < 4; ++r) {
            const float di = __shfl(dv, 4 * quad + r);   // lane l15=4q+r holds row's dinv
            const size_t rowaddr = (tokbase + qt0 + 32 * w + 16 * mf2 + 4 * quad + r) * DIM + h * 64;
            #pragma unroll
            for (int nf2 = 0; nf2 < 4; ++nf2)
                Ob[rowaddr + 16 * nf2 + l15] = f2b(oacc[mf2][nf2][r] * di);
        }
    }
}

// ---------------------------------------------------------------------------
extern "C" void kernel_launch(void* const* d_in, const int* in_sizes, int n_in,
                              void* d_out, int out_size, void* d_ws, size_t ws_size,
                              hipStream_t stream) {
    const float* X  = (const float*)d_in[0];
    const float* Y  = (const float*)d_in[1];
    const float* Z  = (const float*)d_in[2];
    const float* Wq = (const float*)d_in[3];
    const float* Wk = (const float*)d_in[4];
    // d_in[5] = Wv dead in reference forward
    const float* Wo = (const float*)d_in[6];

    char* p = (char*)d_ws;
    const size_t MD = (size_t)M_TOT * DIM;
    short* Qb  = (short*)p; p += MD * 2;
    short* Kb  = (short*)p; p += MD * 2;
    short* Vt  = (short*)p; p += MD * 2;
    short* Ob  = (short*)p; p += MD * 2;
    short* Xb  = (short*)p; p += MD * 2;
    short* Yb  = (short*)p; p += MD * 2;
    short* Zb  = (short*)p; p += MD * 2;
    short* Wtq = (short*)p; p += (size_t)DIM * DIM * 2;
    short* Wtk = (short*)p; p += (size_t)DIM * DIM * 2;
    short* Wto = (short*)p; p += (size_t)DIM * DIM * 2;

    cvt_bf16<<<dim3(M_TOT * DIM / 8 / 256, 3), 256, 0, stream>>>(X, Y, Z, Xb, Yb, Zb);
    prep_wt<<<dim3(8, 8, 3), 256, 0, stream>>>(Wq, Wk, Wo, Wtq, Wtk, Wto);
    proj_gemm<<<dim3(64, 4, 3), 256, 0, stream>>>(Xb, Yb, Zb, Wtq, Wtk, Wto, Qb, Kb, Vt);
    attn_mfma<<<dim3(16, 32), 256, 0, stream>>>(Qb, Kb, Vt, Ob);
    out_gemm<<<dim3(64, 4), 256, 0, stream>>>(Ob, Wto, (float*)d_out);
}